// Round 7
// baseline (860.115 us; speedup 1.0000x reference)
//
#include <hip/hip_runtime.h>
#include <hip/hip_bf16.h>

// Problem constants (fixed by the reference: N=50000, E=400000, D=128, H=256, L=5)
#define NNODES 50000
#define MPAD 50048          // 391 * 128 (gemm row padding)
#define NEDGES 400000
#define DIM 128
#define HID 256
#define NLAYERS 5
#define BONDSZ 13
#define NCOMBO 60           // 5*6*2 bond-attr combinations
#define BN_EPS 1e-5f
#define NCHUNK 49           // ceil(50000/1024)
#define INVN (1.0f / 50000.0f)

typedef __bf16 bf16x8 __attribute__((ext_vector_type(8)));
typedef float f32x4 __attribute__((ext_vector_type(4)));

// ===========================================================================
// CSR build (once per call — edge topology is layer-invariant)
// ===========================================================================
__global__ __launch_bounds__(256) void hist_kernel(
    const int* __restrict__ dst, int* __restrict__ deg)
{
    int e = blockIdx.x * 256 + threadIdx.x;
    if (e < NEDGES) atomicAdd(&deg[dst[e]], 1);
}

__global__ __launch_bounds__(256) void scan_sum(
    const int* __restrict__ deg, int* __restrict__ partial)
{
    __shared__ int red[256];
    int base = blockIdx.x * 1024;
    int s = 0;
    for (int i = threadIdx.x; i < 1024; i += 256) {
        int idx = base + i;
        if (idx < NNODES) s += deg[idx];
    }
    red[threadIdx.x] = s;
    __syncthreads();
    for (int off = 128; off > 0; off >>= 1) {
        if (threadIdx.x < off) red[threadIdx.x] += red[threadIdx.x + off];
        __syncthreads();
    }
    if (threadIdx.x == 0) partial[blockIdx.x] = red[0];
}

__global__ void scan_part(int* __restrict__ partial, int n, int* __restrict__ rowptr_last)
{
    if (threadIdx.x == 0) {
        int acc = 0;
        for (int i = 0; i < n; i++) { int v = partial[i]; partial[i] = acc; acc += v; }
        rowptr_last[0] = acc;
    }
}

__global__ __launch_bounds__(256) void scan_write(
    const int* __restrict__ deg, const int* __restrict__ partial,
    int* __restrict__ row_ptr)
{
    __shared__ int red[256];
    int base = blockIdx.x * 1024;
    int t = threadIdx.x;
    int v[4];
    int s = 0;
    #pragma unroll
    for (int j = 0; j < 4; j++) {
        int idx = base + t * 4 + j;
        v[j] = (idx < NNODES) ? deg[idx] : 0;
        s += v[j];
    }
    red[t] = s;
    __syncthreads();
    for (int off = 1; off < 256; off <<= 1) {
        int x = (t >= off) ? red[t - off] : 0;
        __syncthreads();
        red[t] += x;
        __syncthreads();
    }
    int ex = red[t] - s + partial[blockIdx.x];
    #pragma unroll
    for (int j = 0; j < 4; j++) {
        int idx = base + t * 4 + j;
        if (idx < NNODES) row_ptr[idx] = ex;
        ex += v[j];
    }
}

__global__ __launch_bounds__(256) void scatter_kernel(
    const int* __restrict__ src, const int* __restrict__ dst,
    const int* __restrict__ eattr, const int* __restrict__ row_ptr,
    int* __restrict__ cursor, int2* __restrict__ epack)
{
    int e = blockIdx.x * 256 + threadIdx.x;
    if (e >= NEDGES) return;
    int d = dst[e];
    int pos = row_ptr[d] + atomicAdd(&cursor[d], 1);
    int a0 = eattr[e * 3 + 0];
    int a1 = eattr[e * 3 + 1];
    int a2 = eattr[e * 3 + 2];
    epack[pos] = make_int2(src[e], a0 * 12 + a1 * 2 + a2);   // combo id 0..59
}

// ===========================================================================
// Weight pre-split (once): W -> transposed [n][k] bf16 hi/lo planes
// ===========================================================================
__global__ __launch_bounds__(256) void wsplit_kernel(
    const float* __restrict__ W1, const float* __restrict__ W2,
    __bf16* __restrict__ bt1h, __bf16* __restrict__ bt1l,
    __bf16* __restrict__ bt2h, __bf16* __restrict__ bt2l)
{
    int gid = blockIdx.x * 256 + threadIdx.x;
    const int total1 = NLAYERS * DIM * HID;
    if (gid < total1) {
        int n = gid % HID; int k = (gid / HID) % DIM; int l = gid / (DIM * HID);
        float w = W1[gid];
        __bf16 hi = (__bf16)w;
        int o = (l * HID + n) * DIM + k;
        bt1h[o] = hi; bt1l[o] = (__bf16)(w - (float)hi);
    } else {
        int g = gid - total1;
        if (g < NLAYERS * HID * DIM) {
            int n = g % DIM; int k = (g / DIM) % HID; int l = g / (HID * DIM);
            float w = W2[g];
            __bf16 hi = (__bf16)w;
            int o = (l * DIM + n) * HID + k;
            bt2h[o] = hi; bt2l[o] = (__bf16)(w - (float)hi);
        }
    }
}

// ===========================================================================
// Aggregation + GIN combine (CSR, zero atomics).
//  - combined 60-entry bond table in LDS (1 LDS read/edge instead of 3)
//  - 2 nodes per wave: 32 lanes x float4 each (half the per-edge VALU)
//  - TRANS=1: previous layer's outer BN + inter-layer ReLU fused on gather
//  - writes z as pre-split bf16 hi/lo planes; block 0 zeroes layer stats
// ===========================================================================
template<int TRANS>
__global__ __launch_bounds__(256) void agg_combine(
    const float* __restrict__ hin,
    const int* __restrict__ row_ptr, const int2* __restrict__ epack,
    const float* __restrict__ bond,
    const float* __restrict__ epsv, int lidx,
    const float* __restrict__ csIn, const float* __restrict__ cqIn,
    const float* __restrict__ gamma, const float* __restrict__ beta,
    __bf16* __restrict__ zH, __bf16* __restrict__ zL,
    float* __restrict__ statsZero)
{
    __shared__ float T[BONDSZ * DIM];
    __shared__ float TC[NCOMBO * DIM];
    __shared__ float scs[DIM], shs[DIM];

    for (int i = threadIdx.x; i < BONDSZ * DIM; i += 256) T[i] = bond[i];
    if (TRANS && threadIdx.x < DIM) {
        int c = threadIdx.x;
        float mu = csIn[c] * INVN;
        float var = cqIn[c] * INVN - mu * mu;
        float sv = gamma[c] * rsqrtf(var + BN_EPS);
        scs[c] = sv; shs[c] = beta[c] - mu * sv;
    }
    if (blockIdx.x == 0)
        for (int i = threadIdx.x; i < 768; i += 256) statsZero[i] = 0.f;
    __syncthreads();
    // build combined table: TC[cb] = T[a0] + T[5+a1] + T[11+a2]
    for (int i = threadIdx.x; i < NCOMBO * DIM; i += 256) {
        int cb = i >> 7, c = i & 127;
        int a0 = cb / 12, r = cb - a0 * 12;
        TC[i] = T[a0 * DIM + c] + T[(5 + (r >> 1)) * DIM + c] + T[(11 + (r & 1)) * DIM + c];
    }
    __syncthreads();

    const int wv = threadIdx.x >> 6;
    const int half = (threadIdx.x >> 5) & 1;
    const int li = threadIdx.x & 31;
    const int node = blockIdx.x * 8 + wv * 2 + half;
    const int f = li * 4;

    float4 sc4 = make_float4(1.f, 1.f, 1.f, 1.f);
    float4 sh4 = make_float4(0.f, 0.f, 0.f, 0.f);
    if (TRANS) { sc4 = *(const float4*)&scs[f]; sh4 = *(const float4*)&shs[f]; }

    float ax = 0.f, ay = 0.f, az = 0.f, aw = 0.f;
    const int s = row_ptr[node];
    const int e2 = row_ptr[node + 1];
    int i = s;
    for (; i + 1 < e2; i += 2) {
        int2 ev0 = epack[i];
        int2 ev1 = epack[i + 1];
        float4 g0 = *(const float4*)&hin[(size_t)ev0.x * DIM + f];
        float4 g1 = *(const float4*)&hin[(size_t)ev1.x * DIM + f];
        float4 t0 = *(const float4*)&TC[ev0.y * DIM + f];
        float4 t1 = *(const float4*)&TC[ev1.y * DIM + f];
        if (TRANS) {
            g0.x = fmaxf(g0.x * sc4.x + sh4.x, 0.f); g0.y = fmaxf(g0.y * sc4.y + sh4.y, 0.f);
            g0.z = fmaxf(g0.z * sc4.z + sh4.z, 0.f); g0.w = fmaxf(g0.w * sc4.w + sh4.w, 0.f);
            g1.x = fmaxf(g1.x * sc4.x + sh4.x, 0.f); g1.y = fmaxf(g1.y * sc4.y + sh4.y, 0.f);
            g1.z = fmaxf(g1.z * sc4.z + sh4.z, 0.f); g1.w = fmaxf(g1.w * sc4.w + sh4.w, 0.f);
        }
        ax += fmaxf(g0.x + t0.x, 0.f) + fmaxf(g1.x + t1.x, 0.f);
        ay += fmaxf(g0.y + t0.y, 0.f) + fmaxf(g1.y + t1.y, 0.f);
        az += fmaxf(g0.z + t0.z, 0.f) + fmaxf(g1.z + t1.z, 0.f);
        aw += fmaxf(g0.w + t0.w, 0.f) + fmaxf(g1.w + t1.w, 0.f);
    }
    if (i < e2) {
        int2 ev = epack[i];
        float4 g = *(const float4*)&hin[(size_t)ev.x * DIM + f];
        float4 t = *(const float4*)&TC[ev.y * DIM + f];
        if (TRANS) {
            g.x = fmaxf(g.x * sc4.x + sh4.x, 0.f); g.y = fmaxf(g.y * sc4.y + sh4.y, 0.f);
            g.z = fmaxf(g.z * sc4.z + sh4.z, 0.f); g.w = fmaxf(g.w * sc4.w + sh4.w, 0.f);
        }
        ax += fmaxf(g.x + t.x, 0.f);
        ay += fmaxf(g.y + t.y, 0.f);
        az += fmaxf(g.z + t.z, 0.f);
        aw += fmaxf(g.w + t.w, 0.f);
    }
    float4 hv = *(const float4*)&hin[(size_t)node * DIM + f];
    if (TRANS) {
        hv.x = fmaxf(hv.x * sc4.x + sh4.x, 0.f); hv.y = fmaxf(hv.y * sc4.y + sh4.y, 0.f);
        hv.z = fmaxf(hv.z * sc4.z + sh4.z, 0.f); hv.w = fmaxf(hv.w * sc4.w + sh4.w, 0.f);
    }
    float ep = 1.0f + epsv[lidx];
    float z0 = ep * hv.x + ax, z1 = ep * hv.y + ay;
    float z2 = ep * hv.z + az, z3 = ep * hv.w + aw;
    __bf16 h0 = (__bf16)z0, h1 = (__bf16)z1, h2 = (__bf16)z2, h3 = (__bf16)z3;
    size_t o = (size_t)node * DIM + f;
    typedef __bf16 bf16x4 __attribute__((ext_vector_type(4)));
    bf16x4 vh = {h0, h1, h2, h3};
    bf16x4 vl = {(__bf16)(z0 - (float)h0), (__bf16)(z1 - (float)h1),
                 (__bf16)(z2 - (float)h2), (__bf16)(z3 - (float)h3)};
    *(bf16x4*)(zH + o) = vh;
    *(bf16x4*)(zL + o) = vl;
}

// ===========================================================================
// Barrier-free-K-loop split-precision MFMA GEMM ("persistent B").
//   B panel (64 cols, transposed [col][k] bf16 H/L) staged in LDS once
//   (swizzled chunks -> ~conflict-free), then a barrier-free K-loop:
//   A fragments group-prefetched from global (16 loads in flight), B from LDS.
//   TRANSFORM=0: A = pre-split bf16 H/L planes.
//   TRANSFORM=1: A = fp32; BN(scale/shift from producer stats)+ReLU+split
//                applied in-register.
//   Epilogue: fp32 store + per-column sum/sumsq via wave shuffle reduction ->
//   few LDS atomics -> one global atomic per column per block.
// Block: 256 thr / 4 waves stacked vertically = 128 rows x 64 cols.
// ===========================================================================
template<int K, int NCOLS, int TRANSFORM>
__global__ __launch_bounds__(256) void gemm_pb(
    const __bf16* __restrict__ AH, const __bf16* __restrict__ AL,
    const float* __restrict__ AF,
    const __bf16* __restrict__ BTH, const __bf16* __restrict__ BTL,
    const float* __restrict__ bias,
    const float* __restrict__ csIn, const float* __restrict__ cqIn,
    const float* __restrict__ gamma, const float* __restrict__ beta,
    float* __restrict__ outF,
    float* __restrict__ colsum, float* __restrict__ colsumsq)
{
    constexpr int KC = K / 8;      // 16B chunks per col
    constexpr int NK = K / 32;     // ksteps

    __shared__ __bf16 sBH[64 * K], sBL[64 * K];
    __shared__ float redS[64], redQ[64];
    __shared__ float scs[TRANSFORM ? K : 1], shs[TRANSFORM ? K : 1];

    const int tid = threadIdx.x;
    const int lane = tid & 63;
    const int wv = tid >> 6;
    const int rowL = lane & 15;
    const int quad = lane >> 4;
    const int n0 = blockIdx.x * 64;
    const int r0 = blockIdx.y * 128 + wv * 32;

    // ---- stage B panel once (swizzled chunk layout)
    #pragma unroll
    for (int it = 0; it < (64 * KC) / 256; it++) {
        int c = it * 256 + tid;
        int col = c / KC, kq = c % KC;
        int slot = col * KC + (kq ^ (col & 15));
        size_t g = (size_t)(n0 + col) * K + kq * 8;
        bf16x8 vh = *(const bf16x8*)(BTH + g);
        bf16x8 vl = *(const bf16x8*)(BTL + g);
        *(bf16x8*)(sBH + slot * 8) = vh;
        *(bf16x8*)(sBL + slot * 8) = vl;
    }
    if (tid < 64) { redS[tid] = 0.f; redQ[tid] = 0.f; }
    if (TRANSFORM) {
        for (int c = tid; c < K; c += 256) {
            float mu = csIn[c] * INVN;
            float var = cqIn[c] * INVN - mu * mu;
            float sv = gamma[c] * rsqrtf(var + BN_EPS);
            scs[c] = sv; shs[c] = beta[c] - mu * sv;
        }
    }
    __syncthreads();   // the only barrier before the epilogue

    f32x4 acc[2][4] = {};

    #pragma unroll
    for (int kg = 0; kg < NK; kg += 4) {
        // ---- group-prefetch A fragments: 16 loads in flight
        bf16x8 pH[4][2], pL[4][2];
        float4 pF[4][2][2];
        #pragma unroll
        for (int kk = 0; kk < 4; kk++) {
            const int kb = (kg + kk) * 32 + quad * 8;
            #pragma unroll
            for (int i = 0; i < 2; i++) {
                size_t off = (size_t)(r0 + i * 16 + rowL) * K + kb;
                if (!TRANSFORM) {
                    pH[kk][i] = *(const bf16x8*)(AH + off);
                    pL[kk][i] = *(const bf16x8*)(AL + off);
                } else {
                    pF[kk][i][0] = *(const float4*)(AF + off);
                    pF[kk][i][1] = *(const float4*)(AF + off + 4);
                }
            }
        }
        #pragma unroll
        for (int kk = 0; kk < 4; kk++) {
            const int kt = kg + kk;
            const int kb = kt * 32 + quad * 8;
            bf16x8 aH[2], aL[2];
            #pragma unroll
            for (int i = 0; i < 2; i++) {
                if (!TRANSFORM) {
                    aH[i] = pH[kk][i];
                    aL[i] = pL[kk][i];
                } else {
                    float4 sv0 = *(const float4*)&scs[kb];
                    float4 sv1 = *(const float4*)&scs[kb + 4];
                    float4 tv0 = *(const float4*)&shs[kb];
                    float4 tv1 = *(const float4*)&shs[kb + 4];
                    float fv[8] = {pF[kk][i][0].x, pF[kk][i][0].y, pF[kk][i][0].z, pF[kk][i][0].w,
                                   pF[kk][i][1].x, pF[kk][i][1].y, pF[kk][i][1].z, pF[kk][i][1].w};
                    float sv[8] = {sv0.x, sv0.y, sv0.z, sv0.w, sv1.x, sv1.y, sv1.z, sv1.w};
                    float tv[8] = {tv0.x, tv0.y, tv0.z, tv0.w, tv1.x, tv1.y, tv1.z, tv1.w};
                    #pragma unroll
                    for (int e = 0; e < 8; e++) {
                        float v = fmaxf(fv[e] * sv[e] + tv[e], 0.f);
                        __bf16 hi = (__bf16)v;
                        aH[i][e] = hi;
                        aL[i][e] = (__bf16)(v - (float)hi);
                    }
                }
            }
            const int kqr = kt * 4 + quad;
            #pragma unroll
            for (int j = 0; j < 4; j++) {
                int col = j * 16 + rowL;
                int slot = col * KC + (kqr ^ rowL);
                bf16x8 bH = *(const bf16x8*)(sBH + slot * 8);
                bf16x8 bL = *(const bf16x8*)(sBL + slot * 8);
                #pragma unroll
                for (int i = 0; i < 2; i++) {
                    acc[i][j] = __builtin_amdgcn_mfma_f32_16x16x32_bf16(aH[i], bH, acc[i][j], 0, 0, 0);
                    acc[i][j] = __builtin_amdgcn_mfma_f32_16x16x32_bf16(aL[i], bH, acc[i][j], 0, 0, 0);
                    acc[i][j] = __builtin_amdgcn_mfma_f32_16x16x32_bf16(aH[i], bL, acc[i][j], 0, 0, 0);
                }
            }
        }
    }

    // ---- epilogue: bias, fp32 store, per-column stats via shuffle reduce
    #pragma unroll
    for (int j = 0; j < 4; j++) {
        const int colL = j * 16 + rowL;
        const float bb = bias[n0 + colL];
        float sj = 0.f, qj = 0.f;
        #pragma unroll
        for (int i = 0; i < 2; i++) {
            const int rbase = r0 + i * 16 + quad * 4;
            #pragma unroll
            for (int r = 0; r < 4; r++) {
                const int rr = rbase + r;
                if (rr < NNODES) {
                    float v = acc[i][j][r] + bb;
                    outF[(size_t)rr * NCOLS + n0 + colL] = v;
                    sj += v;
                    qj += v * v;
                }
            }
        }
        sj += __shfl_xor(sj, 16); sj += __shfl_xor(sj, 32);
        qj += __shfl_xor(qj, 16); qj += __shfl_xor(qj, 32);
        if (quad == 0) {
            atomicAdd(&redS[colL], sj);
            atomicAdd(&redQ[colL], qj);
        }
    }
    __syncthreads();
    if (tid < 64) {
        atomicAdd(&colsum[n0 + tid], redS[tid]);
        atomicAdd(&colsumsq[n0 + tid], redQ[tid]);
    }
}

// ===========================================================================
// Final outer BN (no relu), scale/shift computed inline from layer-4 stats.
// ===========================================================================
__global__ __launch_bounds__(256) void bn_out(
    const float* __restrict__ y2, const float* __restrict__ csIn,
    const float* __restrict__ cqIn, const float* __restrict__ gamma,
    const float* __restrict__ beta, float* __restrict__ out)
{
    __shared__ float scs[DIM], shs[DIM];
    if (threadIdx.x < DIM) {
        int c = threadIdx.x;
        float mu = csIn[c] * INVN;
        float var = cqIn[c] * INVN - mu * mu;
        float sv = gamma[c] * rsqrtf(var + BN_EPS);
        scs[c] = sv; shs[c] = beta[c] - mu * sv;
    }
    __syncthreads();
    int i = blockIdx.x * 256 + threadIdx.x;
    if (i >= NNODES * 32) return;
    int c = (i & 31) * 4;
    float4 v = *(const float4*)&y2[(size_t)i * 4];
    float4 s = *(const float4*)&scs[c];
    float4 t = *(const float4*)&shs[c];
    v.x = v.x * s.x + t.x;
    v.y = v.y * s.y + t.y;
    v.z = v.z * s.z + t.z;
    v.w = v.w * s.w + t.w;
    *(float4*)&out[(size_t)i * 4] = v;
}

extern "C" void kernel_launch(void* const* d_in, const int* in_sizes, int n_in,
                              void* d_out, int out_size, void* d_ws, size_t ws_size,
                              hipStream_t stream)
{
    const float* x    = (const float*)d_in[0];
    const int*   ei   = (const int*)d_in[1];
    const int*   ea   = (const int*)d_in[2];
    const float* W1   = (const float*)d_in[3];
    const float* b1   = (const float*)d_in[4];
    const float* g1   = (const float*)d_in[5];
    const float* bb1  = (const float*)d_in[6];
    const float* W2   = (const float*)d_in[7];
    const float* b2   = (const float*)d_in[8];
    const float* epsv = (const float*)d_in[9];
    const float* bond = (const float*)d_in[10];
    const float* g2   = (const float*)d_in[11];
    const float* bb2  = (const float*)d_in[12];
    float* out = (float*)d_out;

    const int* src = ei;
    const int* dstp = ei + NEDGES;

    // ---- workspace layout
    float* ws = (float*)d_ws;
    float* y2    = ws;                            // MPAD*DIM fp32
    float* y1F   = y2 + (size_t)MPAD * DIM;       // MPAD*HID fp32
    float* stats = y1F + (size_t)MPAD * HID;      // 2 sets x 768
    __bf16* zH   = (__bf16*)(stats + 2 * 768);
    __bf16* zL   = zH + (size_t)MPAD * DIM;
    __bf16* bt1h = zL + (size_t)MPAD * DIM;
    __bf16* bt1l = bt1h + (size_t)NLAYERS * DIM * HID;
    __bf16* bt2h = bt1l + (size_t)NLAYERS * DIM * HID;
    __bf16* bt2l = bt2h + (size_t)NLAYERS * HID * DIM;
    int* iws     = (int*)(bt2l + (size_t)NLAYERS * HID * DIM);
    int* deg     = iws;                  // 50000
    int* cursor  = deg + NNODES;         // 50000
    int* row_ptr = cursor + NNODES;      // 50001
    int* partial = row_ptr + NNODES + 1; // 64
    int2* epack  = (int2*)(partial + 64);// 400000 x int2

    // ---- build CSR (dst-sorted packed edge list) + split weights, once
    hipMemsetAsync(deg, 0, 2 * NNODES * sizeof(int), stream);
    hist_kernel<<<(NEDGES + 255) / 256, 256, 0, stream>>>(dstp, deg);
    scan_sum<<<NCHUNK, 256, 0, stream>>>(deg, partial);
    scan_part<<<1, 64, 0, stream>>>(partial, NCHUNK, row_ptr + NNODES);
    scan_write<<<NCHUNK, 256, 0, stream>>>(deg, partial, row_ptr);
    scatter_kernel<<<(NEDGES + 255) / 256, 256, 0, stream>>>(
        src, dstp, ea, row_ptr, cursor, epack);
    wsplit_kernel<<<(2 * NLAYERS * DIM * HID + 255) / 256, 256, 0, stream>>>(
        W1, W2, bt1h, bt1l, bt2h, bt2l);

    for (int l = 0; l < NLAYERS; l++) {
        const int p = l & 1;
        float* cs1 = stats + p * 768;
        float* cq1 = cs1 + HID;
        float* cs2 = cq1 + HID;
        float* cq2 = cs2 + DIM;
        float* statsZ = stats + p * 768;   // whole set, zeroed by agg block 0

        if (l == 0) {
            agg_combine<0><<<NNODES / 8, 256, 0, stream>>>(
                x, row_ptr, epack, bond + (size_t)l * BONDSZ * DIM,
                epsv, l, nullptr, nullptr, nullptr, nullptr, zH, zL, statsZ);
        } else {
            const int pp = (l - 1) & 1;
            float* pcs2 = stats + pp * 768 + 2 * HID;
            float* pcq2 = pcs2 + DIM;
            agg_combine<1><<<NNODES / 8, 256, 0, stream>>>(
                y2, row_ptr, epack, bond + (size_t)l * BONDSZ * DIM,
                epsv, l, pcs2, pcq2, g2 + (size_t)(l - 1) * DIM,
                bb2 + (size_t)(l - 1) * DIM, zH, zL, statsZ);
        }

        // gemm1: [MPAD x 128] @ [128 x 256] -> y1F, grid (4, 391), 32KB LDS
        gemm_pb<DIM, HID, 0><<<dim3(HID / 64, MPAD / 128), 256, 0, stream>>>(
            zH, zL, nullptr,
            bt1h + (size_t)l * HID * DIM, bt1l + (size_t)l * HID * DIM,
            b1 + (size_t)l * HID, nullptr, nullptr, nullptr, nullptr,
            y1F, cs1, cq1);

        // gemm2: [MPAD x 256] @ [256 x 128] -> y2, grid (2, 391), 64KB LDS
        gemm_pb<HID, DIM, 1><<<dim3(DIM / 64, MPAD / 128), 256, 0, stream>>>(
            nullptr, nullptr, y1F,
            bt2h + (size_t)l * DIM * HID, bt2l + (size_t)l * DIM * HID,
            b2 + (size_t)l * DIM, cs1, cq1, g1 + (size_t)l * HID,
            bb1 + (size_t)l * HID, y2, cs2, cq2);
    }

    // final outer BN (layer 4 -> parity 0), no relu
    {
        float* cs2 = stats + 0 * 768 + 2 * HID;
        float* cq2 = cs2 + DIM;
        bn_out<<<(NNODES * 32 + 255) / 256, 256, 0, stream>>>(
            y2, cs2, cq2, g2 + (size_t)4 * DIM, bb2 + (size_t)4 * DIM, out);
    }
}

// Round 8
// 772.144 us; speedup vs baseline: 1.1139x; 1.1139x over previous
//
#include <hip/hip_runtime.h>
#include <hip/hip_bf16.h>

// Problem constants (fixed by the reference: N=50000, E=400000, D=128, H=256, L=5)
#define NNODES 50000
#define MPAD 50048          // 391 * 128 (gemm row padding)
#define NEDGES 400000
#define DIM 128
#define HID 256
#define NLAYERS 5
#define BONDSZ 13
#define NCOMBO 60           // 5*6*2 bond-attr combinations
#define BN_EPS 1e-5f
#define NCHUNK 49           // ceil(50000/1024)
#define INVN (1.0f / 50000.0f)

typedef __bf16 bf16x8 __attribute__((ext_vector_type(8)));
typedef float f32x4 __attribute__((ext_vector_type(4)));

// ===========================================================================
// CSR build (once per call — edge topology is layer-invariant)
// ===========================================================================
__global__ __launch_bounds__(256) void hist_kernel(
    const int* __restrict__ dst, int* __restrict__ deg)
{
    int e = blockIdx.x * 256 + threadIdx.x;
    if (e < NEDGES) atomicAdd(&deg[dst[e]], 1);
}

__global__ __launch_bounds__(256) void scan_sum(
    const int* __restrict__ deg, int* __restrict__ partial)
{
    __shared__ int red[256];
    int base = blockIdx.x * 1024;
    int s = 0;
    for (int i = threadIdx.x; i < 1024; i += 256) {
        int idx = base + i;
        if (idx < NNODES) s += deg[idx];
    }
    red[threadIdx.x] = s;
    __syncthreads();
    for (int off = 128; off > 0; off >>= 1) {
        if (threadIdx.x < off) red[threadIdx.x] += red[threadIdx.x + off];
        __syncthreads();
    }
    if (threadIdx.x == 0) partial[blockIdx.x] = red[0];
}

__global__ void scan_part(int* __restrict__ partial, int n, int* __restrict__ rowptr_last)
{
    if (threadIdx.x == 0) {
        int acc = 0;
        for (int i = 0; i < n; i++) { int v = partial[i]; partial[i] = acc; acc += v; }
        rowptr_last[0] = acc;
    }
}

__global__ __launch_bounds__(256) void scan_write(
    const int* __restrict__ deg, const int* __restrict__ partial,
    int* __restrict__ row_ptr)
{
    __shared__ int red[256];
    int base = blockIdx.x * 1024;
    int t = threadIdx.x;
    int v[4];
    int s = 0;
    #pragma unroll
    for (int j = 0; j < 4; j++) {
        int idx = base + t * 4 + j;
        v[j] = (idx < NNODES) ? deg[idx] : 0;
        s += v[j];
    }
    red[t] = s;
    __syncthreads();
    for (int off = 1; off < 256; off <<= 1) {
        int x = (t >= off) ? red[t - off] : 0;
        __syncthreads();
        red[t] += x;
        __syncthreads();
    }
    int ex = red[t] - s + partial[blockIdx.x];
    #pragma unroll
    for (int j = 0; j < 4; j++) {
        int idx = base + t * 4 + j;
        if (idx < NNODES) row_ptr[idx] = ex;
        ex += v[j];
    }
}

__global__ __launch_bounds__(256) void scatter_kernel(
    const int* __restrict__ src, const int* __restrict__ dst,
    const int* __restrict__ eattr, const int* __restrict__ row_ptr,
    int* __restrict__ cursor, int2* __restrict__ epack)
{
    int e = blockIdx.x * 256 + threadIdx.x;
    if (e >= NEDGES) return;
    int d = dst[e];
    int pos = row_ptr[d] + atomicAdd(&cursor[d], 1);
    int a0 = eattr[e * 3 + 0];
    int a1 = eattr[e * 3 + 1];
    int a2 = eattr[e * 3 + 2];
    epack[pos] = make_int2(src[e], a0 * 12 + a1 * 2 + a2);   // combo id 0..59
}

// ===========================================================================
// Weight pre-split (once): W -> transposed [n][k] bf16 hi/lo planes
// ===========================================================================
__global__ __launch_bounds__(256) void wsplit_kernel(
    const float* __restrict__ W1, const float* __restrict__ W2,
    __bf16* __restrict__ bt1h, __bf16* __restrict__ bt1l,
    __bf16* __restrict__ bt2h, __bf16* __restrict__ bt2l)
{
    int gid = blockIdx.x * 256 + threadIdx.x;
    const int total1 = NLAYERS * DIM * HID;
    if (gid < total1) {
        int n = gid % HID; int k = (gid / HID) % DIM; int l = gid / (DIM * HID);
        float w = W1[gid];
        __bf16 hi = (__bf16)w;
        int o = (l * HID + n) * DIM + k;
        bt1h[o] = hi; bt1l[o] = (__bf16)(w - (float)hi);
    } else {
        int g = gid - total1;
        if (g < NLAYERS * HID * DIM) {
            int n = g % DIM; int k = (g / DIM) % HID; int l = g / (HID * DIM);
            float w = W2[g];
            __bf16 hi = (__bf16)w;
            int o = (l * DIM + n) * HID + k;
            bt2h[o] = hi; bt2l[o] = (__bf16)(w - (float)hi);
        }
    }
}

// ===========================================================================
// Aggregation + GIN combine (CSR, zero atomics).
//  - combined 60-entry bond table in LDS (1 LDS read/edge instead of 3)
//  - 2 nodes per wave: 32 lanes x float4 each
//  - block = 1024 threads (16 waves): 38.4KB LDS charged once per 16 waves
//    -> 2 blocks/CU = 32 waves = full occupancy (R7's 256-thr block sat at 34%)
//  - TRANS=1: previous layer's outer BN + inter-layer ReLU fused on gather
//  - writes z as pre-split bf16 hi/lo planes; block 0 zeroes layer stats
// ===========================================================================
template<int TRANS>
__global__ __launch_bounds__(1024) void agg_combine(
    const float* __restrict__ hin,
    const int* __restrict__ row_ptr, const int2* __restrict__ epack,
    const float* __restrict__ bond,
    const float* __restrict__ epsv, int lidx,
    const float* __restrict__ csIn, const float* __restrict__ cqIn,
    const float* __restrict__ gamma, const float* __restrict__ beta,
    __bf16* __restrict__ zH, __bf16* __restrict__ zL,
    float* __restrict__ statsZero)
{
    __shared__ float T[BONDSZ * DIM];
    __shared__ float TC[NCOMBO * DIM];
    __shared__ float scs[DIM], shs[DIM];

    for (int i = threadIdx.x; i < BONDSZ * DIM; i += 1024) T[i] = bond[i];
    if (TRANS && threadIdx.x < DIM) {
        int c = threadIdx.x;
        float mu = csIn[c] * INVN;
        float var = cqIn[c] * INVN - mu * mu;
        float sv = gamma[c] * rsqrtf(var + BN_EPS);
        scs[c] = sv; shs[c] = beta[c] - mu * sv;
    }
    if (blockIdx.x == 0 && threadIdx.x < 768) statsZero[threadIdx.x] = 0.f;
    __syncthreads();
    // build combined table: TC[cb] = T[a0] + T[5+a1] + T[11+a2]
    for (int i = threadIdx.x; i < NCOMBO * DIM; i += 1024) {
        int cb = i >> 7, c = i & 127;
        int a0 = cb / 12, r = cb - a0 * 12;
        TC[i] = T[a0 * DIM + c] + T[(5 + (r >> 1)) * DIM + c] + T[(11 + (r & 1)) * DIM + c];
    }
    __syncthreads();

    const int wv = threadIdx.x >> 6;            // 0..15
    const int half = (threadIdx.x >> 5) & 1;
    const int li = threadIdx.x & 31;
    const int node = blockIdx.x * 32 + wv * 2 + half;
    if (node >= NNODES) return;
    const int f = li * 4;

    float4 sc4 = make_float4(1.f, 1.f, 1.f, 1.f);
    float4 sh4 = make_float4(0.f, 0.f, 0.f, 0.f);
    if (TRANS) { sc4 = *(const float4*)&scs[f]; sh4 = *(const float4*)&shs[f]; }

    float ax = 0.f, ay = 0.f, az = 0.f, aw = 0.f;
    const int s = row_ptr[node];
    const int e2 = row_ptr[node + 1];
    int i = s;
    for (; i + 1 < e2; i += 2) {
        int2 ev0 = epack[i];
        int2 ev1 = epack[i + 1];
        float4 g0 = *(const float4*)&hin[(size_t)ev0.x * DIM + f];
        float4 g1 = *(const float4*)&hin[(size_t)ev1.x * DIM + f];
        float4 t0 = *(const float4*)&TC[ev0.y * DIM + f];
        float4 t1 = *(const float4*)&TC[ev1.y * DIM + f];
        if (TRANS) {
            g0.x = fmaxf(g0.x * sc4.x + sh4.x, 0.f); g0.y = fmaxf(g0.y * sc4.y + sh4.y, 0.f);
            g0.z = fmaxf(g0.z * sc4.z + sh4.z, 0.f); g0.w = fmaxf(g0.w * sc4.w + sh4.w, 0.f);
            g1.x = fmaxf(g1.x * sc4.x + sh4.x, 0.f); g1.y = fmaxf(g1.y * sc4.y + sh4.y, 0.f);
            g1.z = fmaxf(g1.z * sc4.z + sh4.z, 0.f); g1.w = fmaxf(g1.w * sc4.w + sh4.w, 0.f);
        }
        ax += fmaxf(g0.x + t0.x, 0.f) + fmaxf(g1.x + t1.x, 0.f);
        ay += fmaxf(g0.y + t0.y, 0.f) + fmaxf(g1.y + t1.y, 0.f);
        az += fmaxf(g0.z + t0.z, 0.f) + fmaxf(g1.z + t1.z, 0.f);
        aw += fmaxf(g0.w + t0.w, 0.f) + fmaxf(g1.w + t1.w, 0.f);
    }
    if (i < e2) {
        int2 ev = epack[i];
        float4 g = *(const float4*)&hin[(size_t)ev.x * DIM + f];
        float4 t = *(const float4*)&TC[ev.y * DIM + f];
        if (TRANS) {
            g.x = fmaxf(g.x * sc4.x + sh4.x, 0.f); g.y = fmaxf(g.y * sc4.y + sh4.y, 0.f);
            g.z = fmaxf(g.z * sc4.z + sh4.z, 0.f); g.w = fmaxf(g.w * sc4.w + sh4.w, 0.f);
        }
        ax += fmaxf(g.x + t.x, 0.f);
        ay += fmaxf(g.y + t.y, 0.f);
        az += fmaxf(g.z + t.z, 0.f);
        aw += fmaxf(g.w + t.w, 0.f);
    }
    float4 hv = *(const float4*)&hin[(size_t)node * DIM + f];
    if (TRANS) {
        hv.x = fmaxf(hv.x * sc4.x + sh4.x, 0.f); hv.y = fmaxf(hv.y * sc4.y + sh4.y, 0.f);
        hv.z = fmaxf(hv.z * sc4.z + sh4.z, 0.f); hv.w = fmaxf(hv.w * sc4.w + sh4.w, 0.f);
    }
    float ep = 1.0f + epsv[lidx];
    float z0 = ep * hv.x + ax, z1 = ep * hv.y + ay;
    float z2 = ep * hv.z + az, z3 = ep * hv.w + aw;
    __bf16 h0 = (__bf16)z0, h1 = (__bf16)z1, h2 = (__bf16)z2, h3 = (__bf16)z3;
    size_t o = (size_t)node * DIM + f;
    typedef __bf16 bf16x4 __attribute__((ext_vector_type(4)));
    bf16x4 vh = {h0, h1, h2, h3};
    bf16x4 vl = {(__bf16)(z0 - (float)h0), (__bf16)(z1 - (float)h1),
                 (__bf16)(z2 - (float)h2), (__bf16)(z3 - (float)h3)};
    *(bf16x4*)(zH + o) = vh;
    *(bf16x4*)(zL + o) = vl;
}

// ===========================================================================
// Split-precision MFMA GEMM, persistent-B with K-halved staging.
//   B panel (64 cols, transposed [col][k] bf16 H/L) staged in LDS in rounds
//   of KH<=128 (gemm1: 1 round / 32KB; gemm2: 2 rounds / 32KB instead of a
//   64KB panel — doubles blocks/CU). Swizzled chunk slots -> ~2-way banks.
//   K-loop per round: A fragments group-prefetched from global (16 loads in
//   flight), B from LDS.
//   TRANSFORM=0: A = pre-split bf16 H/L planes.
//   TRANSFORM=1: A = fp32; BN(producer stats)+ReLU+split in-register.
//   Epilogue: fp32 store + per-column sum/sumsq via wave shuffle -> LDS -> 1
//   global atomic per column per block.
// Block: 256 thr / 4 waves stacked vertically = 128 rows x 64 cols.
// ===========================================================================
template<int K, int NCOLS, int TRANSFORM>
__global__ __launch_bounds__(256) void gemm_pb(
    const __bf16* __restrict__ AH, const __bf16* __restrict__ AL,
    const float* __restrict__ AF,
    const __bf16* __restrict__ BTH, const __bf16* __restrict__ BTL,
    const float* __restrict__ bias,
    const float* __restrict__ csIn, const float* __restrict__ cqIn,
    const float* __restrict__ gamma, const float* __restrict__ beta,
    float* __restrict__ outF,
    float* __restrict__ colsum, float* __restrict__ colsumsq)
{
    constexpr int KH = (K > 128) ? 128 : K;   // staged K per round
    constexpr int NH = K / KH;                // rounds
    constexpr int KC = KH / 8;                // 16B chunks per col per round

    __shared__ __bf16 sBH[64 * KH], sBL[64 * KH];
    __shared__ float redS[64], redQ[64];
    __shared__ float scs[TRANSFORM ? K : 1], shs[TRANSFORM ? K : 1];

    const int tid = threadIdx.x;
    const int lane = tid & 63;
    const int wv = tid >> 6;
    const int rowL = lane & 15;
    const int quad = lane >> 4;
    const int n0 = blockIdx.x * 64;
    const int r0 = blockIdx.y * 128 + wv * 32;

    if (tid < 64) { redS[tid] = 0.f; redQ[tid] = 0.f; }
    if (TRANSFORM) {
        for (int c = tid; c < K; c += 256) {
            float mu = csIn[c] * INVN;
            float var = cqIn[c] * INVN - mu * mu;
            float sv = gamma[c] * rsqrtf(var + BN_EPS);
            scs[c] = sv; shs[c] = beta[c] - mu * sv;
        }
    }

    f32x4 acc[2][4] = {};

    #pragma unroll
    for (int h = 0; h < NH; h++) {
        // ---- stage this K-round of B (swizzled chunk layout)
        #pragma unroll
        for (int it = 0; it < (64 * KC) / 256; it++) {
            int c = it * 256 + tid;
            int col = c / KC, kq = c % KC;
            int slot = col * KC + (kq ^ (col & 15));
            size_t g = (size_t)(n0 + col) * K + h * KH + kq * 8;
            bf16x8 vh = *(const bf16x8*)(BTH + g);
            bf16x8 vl = *(const bf16x8*)(BTL + g);
            *(bf16x8*)(sBH + slot * 8) = vh;
            *(bf16x8*)(sBL + slot * 8) = vl;
        }
        __syncthreads();

        #pragma unroll
        for (int kg = 0; kg < KH / 32; kg += 4) {
            // ---- group-prefetch A fragments: 16 loads in flight
            bf16x8 pH[4][2], pL[4][2];
            float4 pF[4][2][2];
            #pragma unroll
            for (int kk = 0; kk < 4; kk++) {
                const int kb = h * KH + (kg + kk) * 32 + quad * 8;
                #pragma unroll
                for (int i = 0; i < 2; i++) {
                    size_t off = (size_t)(r0 + i * 16 + rowL) * K + kb;
                    if (!TRANSFORM) {
                        pH[kk][i] = *(const bf16x8*)(AH + off);
                        pL[kk][i] = *(const bf16x8*)(AL + off);
                    } else {
                        pF[kk][i][0] = *(const float4*)(AF + off);
                        pF[kk][i][1] = *(const float4*)(AF + off + 4);
                    }
                }
            }
            #pragma unroll
            for (int kk = 0; kk < 4; kk++) {
                const int ktl = kg + kk;                  // kstep within round
                const int kb = h * KH + ktl * 32 + quad * 8;
                bf16x8 aH[2], aL[2];
                #pragma unroll
                for (int i = 0; i < 2; i++) {
                    if (!TRANSFORM) {
                        aH[i] = pH[kk][i];
                        aL[i] = pL[kk][i];
                    } else {
                        float4 sv0 = *(const float4*)&scs[kb];
                        float4 sv1 = *(const float4*)&scs[kb + 4];
                        float4 tv0 = *(const float4*)&shs[kb];
                        float4 tv1 = *(const float4*)&shs[kb + 4];
                        float fv[8] = {pF[kk][i][0].x, pF[kk][i][0].y, pF[kk][i][0].z, pF[kk][i][0].w,
                                       pF[kk][i][1].x, pF[kk][i][1].y, pF[kk][i][1].z, pF[kk][i][1].w};
                        float sv[8] = {sv0.x, sv0.y, sv0.z, sv0.w, sv1.x, sv1.y, sv1.z, sv1.w};
                        float tv[8] = {tv0.x, tv0.y, tv0.z, tv0.w, tv1.x, tv1.y, tv1.z, tv1.w};
                        #pragma unroll
                        for (int e = 0; e < 8; e++) {
                            float v = fmaxf(fv[e] * sv[e] + tv[e], 0.f);
                            __bf16 hi = (__bf16)v;
                            aH[i][e] = hi;
                            aL[i][e] = (__bf16)(v - (float)hi);
                        }
                    }
                }
                const int kqr = ktl * 4 + quad;
                #pragma unroll
                for (int j = 0; j < 4; j++) {
                    int col = j * 16 + rowL;
                    int slot = col * KC + (kqr ^ rowL);
                    bf16x8 bH = *(const bf16x8*)(sBH + slot * 8);
                    bf16x8 bL = *(const bf16x8*)(sBL + slot * 8);
                    #pragma unroll
                    for (int i = 0; i < 2; i++) {
                        acc[i][j] = __builtin_amdgcn_mfma_f32_16x16x32_bf16(aH[i], bH, acc[i][j], 0, 0, 0);
                        acc[i][j] = __builtin_amdgcn_mfma_f32_16x16x32_bf16(aL[i], bH, acc[i][j], 0, 0, 0);
                        acc[i][j] = __builtin_amdgcn_mfma_f32_16x16x32_bf16(aH[i], bL, acc[i][j], 0, 0, 0);
                    }
                }
            }
        }
        __syncthreads();   // drain B reads before restaging next round
    }

    // ---- epilogue: bias, fp32 store, per-column stats via shuffle reduce
    #pragma unroll
    for (int j = 0; j < 4; j++) {
        const int colL = j * 16 + rowL;
        const float bb = bias[n0 + colL];
        float sj = 0.f, qj = 0.f;
        #pragma unroll
        for (int i = 0; i < 2; i++) {
            const int rbase = r0 + i * 16 + quad * 4;
            #pragma unroll
            for (int r = 0; r < 4; r++) {
                const int rr = rbase + r;
                if (rr < NNODES) {
                    float v = acc[i][j][r] + bb;
                    outF[(size_t)rr * NCOLS + n0 + colL] = v;
                    sj += v;
                    qj += v * v;
                }
            }
        }
        sj += __shfl_xor(sj, 16); sj += __shfl_xor(sj, 32);
        qj += __shfl_xor(qj, 16); qj += __shfl_xor(qj, 32);
        if (quad == 0) {
            atomicAdd(&redS[colL], sj);
            atomicAdd(&redQ[colL], qj);
        }
    }
    __syncthreads();
    if (tid < 64) {
        atomicAdd(&colsum[n0 + tid], redS[tid]);
        atomicAdd(&colsumsq[n0 + tid], redQ[tid]);
    }
}

// ===========================================================================
// Final outer BN (no relu), scale/shift computed inline from layer-4 stats.
// ===========================================================================
__global__ __launch_bounds__(256) void bn_out(
    const float* __restrict__ y2, const float* __restrict__ csIn,
    const float* __restrict__ cqIn, const float* __restrict__ gamma,
    const float* __restrict__ beta, float* __restrict__ out)
{
    __shared__ float scs[DIM], shs[DIM];
    if (threadIdx.x < DIM) {
        int c = threadIdx.x;
        float mu = csIn[c] * INVN;
        float var = cqIn[c] * INVN - mu * mu;
        float sv = gamma[c] * rsqrtf(var + BN_EPS);
        scs[c] = sv; shs[c] = beta[c] - mu * sv;
    }
    __syncthreads();
    int i = blockIdx.x * 256 + threadIdx.x;
    if (i >= NNODES * 32) return;
    int c = (i & 31) * 4;
    float4 v = *(const float4*)&y2[(size_t)i * 4];
    float4 s = *(const float4*)&scs[c];
    float4 t = *(const float4*)&shs[c];
    v.x = v.x * s.x + t.x;
    v.y = v.y * s.y + t.y;
    v.z = v.z * s.z + t.z;
    v.w = v.w * s.w + t.w;
    *(float4*)&out[(size_t)i * 4] = v;
}

extern "C" void kernel_launch(void* const* d_in, const int* in_sizes, int n_in,
                              void* d_out, int out_size, void* d_ws, size_t ws_size,
                              hipStream_t stream)
{
    const float* x    = (const float*)d_in[0];
    const int*   ei   = (const int*)d_in[1];
    const int*   ea   = (const int*)d_in[2];
    const float* W1   = (const float*)d_in[3];
    const float* b1   = (const float*)d_in[4];
    const float* g1   = (const float*)d_in[5];
    const float* bb1  = (const float*)d_in[6];
    const float* W2   = (const float*)d_in[7];
    const float* b2   = (const float*)d_in[8];
    const float* epsv = (const float*)d_in[9];
    const float* bond = (const float*)d_in[10];
    const float* g2   = (const float*)d_in[11];
    const float* bb2  = (const float*)d_in[12];
    float* out = (float*)d_out;

    const int* src = ei;
    const int* dstp = ei + NEDGES;

    // ---- workspace layout
    float* ws = (float*)d_ws;
    float* y2    = ws;                            // MPAD*DIM fp32
    float* y1F   = y2 + (size_t)MPAD * DIM;       // MPAD*HID fp32
    float* stats = y1F + (size_t)MPAD * HID;      // 2 sets x 768
    __bf16* zH   = (__bf16*)(stats + 2 * 768);
    __bf16* zL   = zH + (size_t)MPAD * DIM;
    __bf16* bt1h = zL + (size_t)MPAD * DIM;
    __bf16* bt1l = bt1h + (size_t)NLAYERS * DIM * HID;
    __bf16* bt2h = bt1l + (size_t)NLAYERS * DIM * HID;
    __bf16* bt2l = bt2h + (size_t)NLAYERS * HID * DIM;
    int* iws     = (int*)(bt2l + (size_t)NLAYERS * HID * DIM);
    int* deg     = iws;                  // 50000
    int* cursor  = deg + NNODES;         // 50000
    int* row_ptr = cursor + NNODES;      // 50001
    int* partial = row_ptr + NNODES + 1; // 64
    int2* epack  = (int2*)(partial + 64);// 400000 x int2

    // ---- build CSR (dst-sorted packed edge list) + split weights, once
    hipMemsetAsync(deg, 0, 2 * NNODES * sizeof(int), stream);
    hist_kernel<<<(NEDGES + 255) / 256, 256, 0, stream>>>(dstp, deg);
    scan_sum<<<NCHUNK, 256, 0, stream>>>(deg, partial);
    scan_part<<<1, 64, 0, stream>>>(partial, NCHUNK, row_ptr + NNODES);
    scan_write<<<NCHUNK, 256, 0, stream>>>(deg, partial, row_ptr);
    scatter_kernel<<<(NEDGES + 255) / 256, 256, 0, stream>>>(
        src, dstp, ea, row_ptr, cursor, epack);
    wsplit_kernel<<<(2 * NLAYERS * DIM * HID + 255) / 256, 256, 0, stream>>>(
        W1, W2, bt1h, bt1l, bt2h, bt2l);

    for (int l = 0; l < NLAYERS; l++) {
        const int p = l & 1;
        float* cs1 = stats + p * 768;
        float* cq1 = cs1 + HID;
        float* cs2 = cq1 + HID;
        float* cq2 = cs2 + DIM;
        float* statsZ = stats + p * 768;   // whole set, zeroed by agg block 0

        if (l == 0) {
            agg_combine<0><<<(NNODES + 31) / 32, 1024, 0, stream>>>(
                x, row_ptr, epack, bond + (size_t)l * BONDSZ * DIM,
                epsv, l, nullptr, nullptr, nullptr, nullptr, zH, zL, statsZ);
        } else {
            const int pp = (l - 1) & 1;
            float* pcs2 = stats + pp * 768 + 2 * HID;
            float* pcq2 = pcs2 + DIM;
            agg_combine<1><<<(NNODES + 31) / 32, 1024, 0, stream>>>(
                y2, row_ptr, epack, bond + (size_t)l * BONDSZ * DIM,
                epsv, l, pcs2, pcq2, g2 + (size_t)(l - 1) * DIM,
                bb2 + (size_t)(l - 1) * DIM, zH, zL, statsZ);
        }

        // gemm1: [MPAD x 128] @ [128 x 256] -> y1F, grid (4, 391), 32KB LDS
        gemm_pb<DIM, HID, 0><<<dim3(HID / 64, MPAD / 128), 256, 0, stream>>>(
            zH, zL, nullptr,
            bt1h + (size_t)l * HID * DIM, bt1l + (size_t)l * HID * DIM,
            b1 + (size_t)l * HID, nullptr, nullptr, nullptr, nullptr,
            y1F, cs1, cq1);

        // gemm2: [MPAD x 256] @ [256 x 128] -> y2, grid (2, 391), 32KB LDS (2 rounds)
        gemm_pb<HID, DIM, 1><<<dim3(DIM / 64, MPAD / 128), 256, 0, stream>>>(
            nullptr, nullptr, y1F,
            bt2h + (size_t)l * DIM * HID, bt2l + (size_t)l * DIM * HID,
            b2 + (size_t)l * DIM, cs1, cq1, g1 + (size_t)l * HID,
            bb1 + (size_t)l * HID, y2, cs2, cq2);
    }

    // final outer BN (layer 4 -> parity 0), no relu
    {
        float* cs2 = stats + 0 * 768 + 2 * HID;
        float* cq2 = cs2 + DIM;
        bn_out<<<(NNODES * 32 + 255) / 256, 256, 0, stream>>>(
            y2, cs2, cq2, g2 + (size_t)4 * DIM, bb2 + (size_t)4 * DIM, out);
    }
}